// Round 3
// baseline (1280.050 us; speedup 1.0000x reference)
//
#include <hip/hip_runtime.h>
#include <math.h>

#define NPTS 8192
#define DIM 32
#define TILE 128
#define NT (NPTS / TILE)              // 64 tiles per side
#define NTP (NT * (NT + 1) / 2)       // 2080 upper-tri tile pairs
#define NBINS 4096
#define BIN_SCALE 20.0f               // bins per unit d^2 -> covers d^2 in [0, 204.8]
#define NR 16
#define MAXP 512
#define TM 8
#define TN 4

// ---------------- kernel 0: squared norms ----------------
__global__ void k_sq(const float* __restrict__ pts, float* __restrict__ sq) {
    int i = blockIdx.x * blockDim.x + threadIdx.x;
    if (i >= NPTS) return;
    const float4* r = (const float4*)(pts + (size_t)i * DIM);
    float s = 0.f;
#pragma unroll
    for (int q = 0; q < DIM / 4; ++q) {
        float4 v = r[q];
        s += v.x * v.x + v.y * v.y + v.z * v.z + v.w * v.w;
    }
    sq[i] = s;
}

// ---------------- kernel 1: pairwise d^2 histogram ----------------
// 512 threads = 32x16 grid; each thread owns 8 rows x 4 strided cols.
// NO __launch_bounds__: a 128-VGPR cap made the scheduler's hoisted
// ds_read fragments spill acc to scratch (GB-scale HBM traffic, r1/r2).
__global__
void k_hist(const float4* __restrict__ p4, const float* __restrict__ sq,
            unsigned* __restrict__ parts) {
    __shared__ unsigned hist[NBINS];          // 16 KB
    __shared__ float4 At[8][TILE];            // 16 KB  (seg-major, cols XOR seg)
    __shared__ float4 Bt[8][TILE];            // 16 KB
    const int tid = threadIdx.x;
    const int tx = tid & 31, ty = tid >> 5;
    for (int b = tid; b < NBINS; b += 512) hist[b] = 0u;
    const int P = gridDim.x;

    for (int tp = blockIdx.x; tp < NTP; tp += P) {
        // decode upper-triangular tile pair (ti <= tj)
        int ti = 0, rr = tp;
        while (rr >= NT - ti) { rr -= NT - ti; ++ti; }
        const int tj = ti + rr;

        __syncthreads();   // previous iteration's reads of At/Bt done
        // stage tiles: global reads perfectly contiguous (idx == p*8+seg),
        // LDS column swizzled by ^seg -> staging writes spread over bank quads
#pragma unroll
        for (int q = 0; q < 2; ++q) {
            const int idx = tid + 512 * q;    // 0..1023
            const int seg = idx & 7;          // which 4 coords
            const int p = idx >> 3;           // point within tile
            const int sp = p ^ seg;
            At[seg][sp] = p4[(size_t)ti * 1024 + idx];
            Bt[seg][sp] = p4[(size_t)tj * 1024 + idx];
        }
        __syncthreads();

        float acc[TM][TN];
#pragma unroll
        for (int m = 0; m < TM; ++m)
#pragma unroll
            for (int n = 0; n < TN; ++n) acc[m][n] = 0.f;

#pragma unroll
        for (int seg = 0; seg < 8; ++seg) {
            float4 bv[TN];
#pragma unroll
            for (int n = 0; n < TN; ++n)
                bv[n] = Bt[seg][(n * 32 + tx) ^ seg];   // contiguous, conflict-free
#pragma unroll
            for (int m = 0; m < TM; ++m) {
                const float4 a = At[seg][(ty * 8 + m) ^ seg];  // half-wave broadcast
#pragma unroll
                for (int n = 0; n < TN; ++n) {
                    acc[m][n] = fmaf(a.x, bv[n].x, acc[m][n]);
                    acc[m][n] = fmaf(a.y, bv[n].y, acc[m][n]);
                    acc[m][n] = fmaf(a.z, bv[n].z, acc[m][n]);
                    acc[m][n] = fmaf(a.w, bv[n].w, acc[m][n]);
                }
            }
        }

        float sA[TM], sB[TN];
#pragma unroll
        for (int m = 0; m < TM; ++m) sA[m] = sq[ti * TILE + ty * 8 + m];
#pragma unroll
        for (int n = 0; n < TN; ++n) sB[n] = sq[tj * TILE + n * 32 + tx];

        const bool diag = (ti == tj);
#pragma unroll
        for (int m = 0; m < TM; ++m) {
#pragma unroll
            for (int n = 0; n < TN; ++n) {
                const float d2 = fmaf(-2.f, acc[m][n], sA[m] + sB[n]);
                const float bf_ = fminf(fmaxf(d2, 0.f) * BIN_SCALE, (float)(NBINS - 1));
                const int bin = (int)bf_;
                if (!diag || ((ty * 8 + m) < (n * 32 + tx)))
                    atomicAdd(&hist[bin], 1u);
            }
        }
    }

    __syncthreads();
    unsigned* my = parts + (size_t)blockIdx.x * NBINS;
    for (int b = tid; b < NBINS; b += 512) my[b] = hist[b];
}

// ---------------- kernel 2: reduce partials, sigmoid sums ----------------
__global__ void k_sums(const unsigned* __restrict__ parts, int P,
                       const float* __restrict__ rvals, double* __restrict__ sums) {
    const int b = blockIdx.x * 256 + threadIdx.x;
    unsigned long long c;
    {
        unsigned c8[8];
#pragma unroll
        for (int u = 0; u < 8; ++u) c8[u] = 0u;
        int p = 0;
        for (; p + 8 <= P; p += 8) {          // 8 independent loads in flight
#pragma unroll
            for (int u = 0; u < 8; ++u)
                c8[u] += parts[(size_t)(p + u) * NBINS + b];
        }
        for (; p < P; ++p) c8[0] += parts[(size_t)p * NBINS + b];
        unsigned long long t = 0;
#pragma unroll
        for (int u = 0; u < 8; ++u) t += c8[u];
        c = t;
    }

    double local[NR + 1];
#pragma unroll
    for (int t = 0; t < NR; ++t) local[t] = 0.0;
    local[NR] = (double)c;   // pair count

    if (c) {
        const double d = sqrt(((double)b + 0.5) / (double)BIN_SCALE);
#pragma unroll
        for (int t = 0; t < NR; ++t) {
            const double x = 10.0 * ((double)rvals[t] - d);
            double s;
            if (x >= 0.0) s = 1.0 / (1.0 + exp(-x));
            else          { const double e = exp(x); s = e / (1.0 + e); }
            local[t] = (double)c * s;
        }
    }

    // wave(64) reduction, then one atomic per wave per value
#pragma unroll
    for (int off = 32; off > 0; off >>= 1) {
#pragma unroll
        for (int t = 0; t <= NR; ++t)
            local[t] += __shfl_down(local[t], off);
    }
    if ((threadIdx.x & 63) == 0) {
#pragma unroll
        for (int t = 0; t <= NR; ++t) atomicAdd(&sums[t], local[t]);
    }
}

// ---------------- kernel 3: log-log regression ----------------
__global__ void k_fit(const double* __restrict__ sums, const float* __restrict__ rvals,
                      float* __restrict__ out) {
    const double cnt = sums[NR];
    double Sx = 0, Sy = 0, Sxx = 0, Sxy = 0;
#pragma unroll
    for (int t = 0; t < NR; ++t) {
        const double x = log((double)rvals[t]);
        const double y = log(sums[t] / cnt);
        Sx += x; Sy += y; Sxx += x * x; Sxy += x * y;
    }
    const double R = (double)NR;
    const double slope = (R * Sxy - Sx * Sy) / (R * Sxx - Sx * Sx);
    out[0] = (float)(-slope);
}

extern "C" void kernel_launch(void* const* d_in, const int* in_sizes, int n_in,
                              void* d_out, int out_size, void* d_ws, size_t ws_size,
                              hipStream_t stream) {
    const float* pts = (const float*)d_in[0];
    const float* rv  = (const float*)d_in[1];
    float* out = (float*)d_out;
    char* ws = (char*)d_ws;

    float* sq = (float*)ws;                        // 32 KB
    const size_t off_parts = 32768;
    size_t avail = (ws_size > off_parts + 1024) ? (ws_size - off_parts - 1024) : 0;
    int P = (int)(avail / ((size_t)NBINS * sizeof(unsigned)));
    if (P > MAXP) P = MAXP;
    if (P < 1) P = 1;
    unsigned* parts = (unsigned*)(ws + off_parts);
    double* sums = (double*)(ws + off_parts + (size_t)P * NBINS * sizeof(unsigned));

    hipMemsetAsync(sums, 0, (NR + 1) * sizeof(double), stream);
    k_sq<<<NPTS / 256, 256, 0, stream>>>(pts, sq);
    k_hist<<<P, 512, 0, stream>>>((const float4*)pts, sq, parts);
    k_sums<<<NBINS / 256, 256, 0, stream>>>(parts, P, rv, sums);
    k_fit<<<1, 1, 0, stream>>>(sums, rv, out);
}

// Round 4
// 547.895 us; speedup vs baseline: 2.3363x; 2.3363x over previous
//
#include <hip/hip_runtime.h>
#include <math.h>

#define NPTS 8192
#define DIM 32
#define TILE 128
#define NT (NPTS / TILE)              // 64 tiles per side
#define NTP (NT * (NT + 1) / 2)       // 2080 upper-tri tile pairs
#define NBINS 4096
#define BIN_SCALE 20.0f               // bins per unit d^2 -> covers d^2 in [0, 204.8]
#define NR 16
#define MAXP 512

// ---------------- kernel 0: squared norms ----------------
__global__ void k_sq(const float* __restrict__ pts, float* __restrict__ sq) {
    int i = blockIdx.x * blockDim.x + threadIdx.x;
    if (i >= NPTS) return;
    const float4* r = (const float4*)(pts + (size_t)i * DIM);
    float s = 0.f;
#pragma unroll
    for (int q = 0; q < DIM / 4; ++q) {
        float4 v = r[q];
        s += v.x * v.x + v.y * v.y + v.z * v.z + v.w * v.w;
    }
    sq[i] = s;
}

// ---------------- kernel 1: pairwise d^2 histogram ----------------
// 512 threads = 32x16 grid; each thread owns 8 rows x 4 strided cols.
// ALL hot-loop state is NAMED SCALARS (no arrays) so nothing can be
// lowered to scratch: rounds 1-3 all showed GB-scale scratch traffic
// (VALUBusy <8%, HBM-bound) from array demotion at any launch_bounds.
// sched_barrier(0) per k-segment bounds the scheduler's hoist window.

#define FMA4(C, A, B) \
    C = fmaf(A.x, B.x, C); C = fmaf(A.y, B.y, C); \
    C = fmaf(A.z, B.z, C); C = fmaf(A.w, B.w, C);

#define ROW(m) { \
    const float4 a = At[seg][((ty << 3) + m) ^ seg]; \
    FMA4(c##m##0, a, bv0) FMA4(c##m##1, a, bv1) \
    FMA4(c##m##2, a, bv2) FMA4(c##m##3, a, bv3) }

#define SEGBLK(S) { \
    const int seg = S; \
    const float4 bv0 = Bt[seg][(tx) ^ seg]; \
    const float4 bv1 = Bt[seg][(32 + tx) ^ seg]; \
    const float4 bv2 = Bt[seg][(64 + tx) ^ seg]; \
    const float4 bv3 = Bt[seg][(96 + tx) ^ seg]; \
    ROW(0) ROW(1) ROW(2) ROW(3) ROW(4) ROW(5) ROW(6) ROW(7) \
    __builtin_amdgcn_sched_barrier(0); }

#define DECL_ROW(m) float c##m##0 = 0.f, c##m##1 = 0.f, c##m##2 = 0.f, c##m##3 = 0.f;

#define EPI(m, n) { \
    const float d2 = fmaf(-2.f, c##m##n, sA##m + sB##n); \
    const int bin = (int)fminf(fmaxf(d2, 0.f) * BIN_SCALE, (float)(NBINS - 1)); \
    if (!diag || (((ty << 3) + m) < (n * 32 + tx))) atomicAdd(&hist[bin], 1u); }

__global__ __launch_bounds__(512, 2)
void k_hist(const float4* __restrict__ p4, const float* __restrict__ sq,
            unsigned* __restrict__ parts) {
    __shared__ unsigned hist[NBINS];          // 16 KB
    __shared__ float4 At[8][TILE];            // 16 KB  (seg-major, cols XOR seg)
    __shared__ float4 Bt[8][TILE];            // 16 KB
    const int tid = threadIdx.x;
    const int tx = tid & 31, ty = tid >> 5;
    for (int b = tid; b < NBINS; b += 512) hist[b] = 0u;
    const int P = gridDim.x;

    for (int tp = blockIdx.x; tp < NTP; tp += P) {
        // decode upper-triangular tile pair (ti <= tj)
        int ti = 0, rr = tp;
        while (rr >= NT - ti) { rr -= NT - ti; ++ti; }
        const int tj = ti + rr;

        __syncthreads();   // previous iteration's reads of At/Bt done
        // stage tiles: global reads perfectly contiguous (idx == p*8+seg),
        // LDS column swizzled by ^seg -> balanced across bank quads
#pragma unroll
        for (int q = 0; q < 2; ++q) {
            const int idx = tid + 512 * q;    // 0..1023
            const int seg = idx & 7;          // which 4 coords
            const int p = idx >> 3;           // point within tile
            const int sp = p ^ seg;
            At[seg][sp] = p4[(size_t)ti * 1024 + idx];
            Bt[seg][sp] = p4[(size_t)tj * 1024 + idx];
        }
        __syncthreads();

        DECL_ROW(0) DECL_ROW(1) DECL_ROW(2) DECL_ROW(3)
        DECL_ROW(4) DECL_ROW(5) DECL_ROW(6) DECL_ROW(7)

        SEGBLK(0) SEGBLK(1) SEGBLK(2) SEGBLK(3)
        SEGBLK(4) SEGBLK(5) SEGBLK(6) SEGBLK(7)

        const float sA0 = sq[ti * TILE + (ty << 3) + 0];
        const float sA1 = sq[ti * TILE + (ty << 3) + 1];
        const float sA2 = sq[ti * TILE + (ty << 3) + 2];
        const float sA3 = sq[ti * TILE + (ty << 3) + 3];
        const float sA4 = sq[ti * TILE + (ty << 3) + 4];
        const float sA5 = sq[ti * TILE + (ty << 3) + 5];
        const float sA6 = sq[ti * TILE + (ty << 3) + 6];
        const float sA7 = sq[ti * TILE + (ty << 3) + 7];
        const float sB0 = sq[tj * TILE + 0 * 32 + tx];
        const float sB1 = sq[tj * TILE + 1 * 32 + tx];
        const float sB2 = sq[tj * TILE + 2 * 32 + tx];
        const float sB3 = sq[tj * TILE + 3 * 32 + tx];

        const bool diag = (ti == tj);
        EPI(0,0) EPI(0,1) EPI(0,2) EPI(0,3)
        EPI(1,0) EPI(1,1) EPI(1,2) EPI(1,3)
        EPI(2,0) EPI(2,1) EPI(2,2) EPI(2,3)
        EPI(3,0) EPI(3,1) EPI(3,2) EPI(3,3)
        EPI(4,0) EPI(4,1) EPI(4,2) EPI(4,3)
        EPI(5,0) EPI(5,1) EPI(5,2) EPI(5,3)
        EPI(6,0) EPI(6,1) EPI(6,2) EPI(6,3)
        EPI(7,0) EPI(7,1) EPI(7,2) EPI(7,3)
    }

    __syncthreads();
    unsigned* my = parts + (size_t)blockIdx.x * NBINS;
    for (int b = tid; b < NBINS; b += 512) my[b] = hist[b];
}

// ---------------- kernel 2: reduce partials, sigmoid sums ----------------
__global__ void k_sums(const unsigned* __restrict__ parts, int P,
                       const float* __restrict__ rvals, double* __restrict__ sums) {
    const int b = blockIdx.x * 256 + threadIdx.x;
    unsigned long long c;
    {
        unsigned c8[8];
#pragma unroll
        for (int u = 0; u < 8; ++u) c8[u] = 0u;
        int p = 0;
        for (; p + 8 <= P; p += 8) {          // 8 independent loads in flight
#pragma unroll
            for (int u = 0; u < 8; ++u)
                c8[u] += parts[(size_t)(p + u) * NBINS + b];
        }
        for (; p < P; ++p) c8[0] += parts[(size_t)p * NBINS + b];
        unsigned long long t = 0;
#pragma unroll
        for (int u = 0; u < 8; ++u) t += c8[u];
        c = t;
    }

    double local[NR + 1];
#pragma unroll
    for (int t = 0; t < NR; ++t) local[t] = 0.0;
    local[NR] = (double)c;   // pair count

    if (c) {
        const double d = sqrt(((double)b + 0.5) / (double)BIN_SCALE);
#pragma unroll
        for (int t = 0; t < NR; ++t) {
            const double x = 10.0 * ((double)rvals[t] - d);
            double s;
            if (x >= 0.0) s = 1.0 / (1.0 + exp(-x));
            else          { const double e = exp(x); s = e / (1.0 + e); }
            local[t] = (double)c * s;
        }
    }

    // wave(64) reduction, then one atomic per wave per value
#pragma unroll
    for (int off = 32; off > 0; off >>= 1) {
#pragma unroll
        for (int t = 0; t <= NR; ++t)
            local[t] += __shfl_down(local[t], off);
    }
    if ((threadIdx.x & 63) == 0) {
#pragma unroll
        for (int t = 0; t <= NR; ++t) atomicAdd(&sums[t], local[t]);
    }
}

// ---------------- kernel 3: log-log regression ----------------
__global__ void k_fit(const double* __restrict__ sums, const float* __restrict__ rvals,
                      float* __restrict__ out) {
    const double cnt = sums[NR];
    double Sx = 0, Sy = 0, Sxx = 0, Sxy = 0;
#pragma unroll
    for (int t = 0; t < NR; ++t) {
        const double x = log((double)rvals[t]);
        const double y = log(sums[t] / cnt);
        Sx += x; Sy += y; Sxx += x * x; Sxy += x * y;
    }
    const double R = (double)NR;
    const double slope = (R * Sxy - Sx * Sy) / (R * Sxx - Sx * Sx);
    out[0] = (float)(-slope);
}

extern "C" void kernel_launch(void* const* d_in, const int* in_sizes, int n_in,
                              void* d_out, int out_size, void* d_ws, size_t ws_size,
                              hipStream_t stream) {
    const float* pts = (const float*)d_in[0];
    const float* rv  = (const float*)d_in[1];
    float* out = (float*)d_out;
    char* ws = (char*)d_ws;

    float* sq = (float*)ws;                        // 32 KB
    const size_t off_parts = 32768;
    size_t avail = (ws_size > off_parts + 1024) ? (ws_size - off_parts - 1024) : 0;
    int P = (int)(avail / ((size_t)NBINS * sizeof(unsigned)));
    if (P > MAXP) P = MAXP;
    if (P < 1) P = 1;
    unsigned* parts = (unsigned*)(ws + off_parts);
    double* sums = (double*)(ws + off_parts + (size_t)P * NBINS * sizeof(unsigned));

    hipMemsetAsync(sums, 0, (NR + 1) * sizeof(double), stream);
    k_sq<<<NPTS / 256, 256, 0, stream>>>(pts, sq);
    k_hist<<<P, 512, 0, stream>>>((const float4*)pts, sq, parts);
    k_sums<<<NBINS / 256, 256, 0, stream>>>(parts, P, rv, sums);
    k_fit<<<1, 1, 0, stream>>>(sums, rv, out);
}